// Round 4
// baseline (2742.546 us; speedup 1.0000x reference)
//
#include <hip/hip_runtime.h>
#include <hip/hip_fp16.h>

// LightGCN 2-layer propagation on MI355X — R13: R12 (entry-centric
// LDS-atomic gather, CSR fill deleted) resubmitted with relaxed launch
// bounds after an infra-side container failure.
//
// Design (from R12):
//   per bucket (147 nodes): stream (loc,nbr) entries, gather fp16 row[nbr],
//   accumulate into LDS acc[loc][.] via ds_add_f32. Commutative sum =>
//   bucketing is the only sort needed. fill_local/adj/start/deg deleted.
// Gather geometry: 1024 buckets -> 4 blocks/CU exactly (512 thr, 38.3 KB
// LDS), no quantization tail.
// LDS acc row stride = 65 floats: bank = (loc + 8*s + i) % 32 -> random loc
// spreads a wave's 64 lanes ~2-way (free per m136); stride 64 would be
// 16-way (~5.7x).

#define NUM_USERS 100000
#define NUM_ITEMS 50000
#define N_NODES   150000
#define NUM_EDGES 2000000
#define EMB_D     64

#define BNODE  147                                 // nodes per bucket
#define NBUCK  1024                                // exactly 4 blocks/CU at 512 thr
#define MAGIC  29217465u                           // ceil(2^32/147), exact for n<150016
#define P      512                                 // producer blocks
#define E4     (NUM_EDGES / 4)                     // 500000 int4 per edge stream
#define CE4    ((E4 + P - 1) / P)                  // 977 int4 per block
#define NTOT   (NBUCK * P)                         // 524288 = 512 * 1024
#define SBLK   (NTOT / 1024)                       // 512 scan blocks

#define ASTRIDE 65                                 // LDS acc row stride (floats)
#define ACC4    ((BNODE * ASTRIDE + 3) / 4 + 1)    // float4 count (padded)

#define CPYB   1024                                // concat-convert blocks
#define H8CNT  (N_NODES * (EMB_D / 8))             // 1.2M 16-byte chunks
#define UF4    (NUM_USERS * (EMB_D / 4))           // user float4 count

struct alignas(16) h8vec { __half2 h[4]; };        // 8 halves = 16 B

__device__ __forceinline__ unsigned buck(unsigned n) {
    return (unsigned)(((unsigned long long)n * MAGIC) >> 32);
}

// ---- A) per-block bucket histogram (int4 edge loads) + fp16 concat ----
__global__ __launch_bounds__(256) void k_count_concat(const int* __restrict__ eidx,
                                                      int* __restrict__ cnt,
                                                      const float4* __restrict__ user4,
                                                      const float4* __restrict__ item4,
                                                      h8vec* __restrict__ tab) {
    int g = blockIdx.x, tid = threadIdx.x;
    if (g >= P) {
        int i = (g - P) * 256 + tid;
        const int stride = CPYB * 256;
        for (; i < H8CNT; i += stride) {
            const float4* s = (i * 2 < UF4) ? (user4 + (size_t)i * 2)
                                            : (item4 + ((size_t)i * 2 - UF4));
            float4 a = s[0], b = s[1];
            h8vec o;
            o.h[0] = __floats2half2_rn(a.x, a.y);
            o.h[1] = __floats2half2_rn(a.z, a.w);
            o.h[2] = __floats2half2_rn(b.x, b.y);
            o.h[3] = __floats2half2_rn(b.z, b.w);
            tab[i] = o;
        }
        return;
    }
    __shared__ int hist[NBUCK];
    for (int b = tid; b < NBUCK; b += 256) hist[b] = 0;
    __syncthreads();
    const int4* r4 = (const int4*)eidx;
    const int4* c4 = (const int4*)(eidx + NUM_EDGES);
    int lo = g * CE4, hi = min(E4, lo + CE4);
    for (int j = lo + tid; j < hi; j += 256) {
        int4 a = r4[j], b = c4[j];
        atomicAdd(&hist[buck(a.x)], 1);
        atomicAdd(&hist[buck(a.y)], 1);
        atomicAdd(&hist[buck(a.z)], 1);
        atomicAdd(&hist[buck(a.w)], 1);
        atomicAdd(&hist[buck(b.x)], 1);
        atomicAdd(&hist[buck(b.y)], 1);
        atomicAdd(&hist[buck(b.z)], 1);
        atomicAdd(&hist[buck(b.w)], 1);
    }
    __syncthreads();
    for (int b = tid; b < NBUCK; b += 256) cnt[b * P + g] = hist[b];
}

// ---- B1) local exclusive scan: 1024 elems/block (256 thr x 4) ----
__global__ __launch_bounds__(256) void k_scan1(int* __restrict__ cnt,
                                               int* __restrict__ blocksums) {
    __shared__ int lds[256];
    int base = blockIdx.x * 1024 + threadIdx.x * 4;
    int v0 = cnt[base + 0], v1 = cnt[base + 1], v2 = cnt[base + 2], v3 = cnt[base + 3];
    int t = v0 + v1 + v2 + v3;
    lds[threadIdx.x] = t;
    __syncthreads();
    int val = t;
    for (int off = 1; off < 256; off <<= 1) {
        int add = (threadIdx.x >= off) ? lds[threadIdx.x - off] : 0;
        __syncthreads();
        val += add;
        lds[threadIdx.x] = val;
        __syncthreads();
    }
    int run = val - t;
    cnt[base + 0] = run; run += v0;
    cnt[base + 1] = run; run += v1;
    cnt[base + 2] = run; run += v2;
    cnt[base + 3] = run;
    if (threadIdx.x == 255) blocksums[blockIdx.x] = val;
}

// ---- B2) 1-block exclusive scan of 512 partials ----
__global__ __launch_bounds__(512) void k_scan2(const int* __restrict__ blocksums,
                                               int* __restrict__ blockoffs) {
    __shared__ int lds[512];
    int t = threadIdx.x;
    int v = (t < SBLK) ? blocksums[t] : 0;
    lds[t] = v;
    __syncthreads();
    int val = v;
    for (int off = 1; off < 512; off <<= 1) {
        int add = (t >= off) ? lds[t - off] : 0;
        __syncthreads();
        val += add;
        lds[t] = val;
        __syncthreads();
    }
    if (t < SBLK) blockoffs[t] = val - v;
}

// ---- C) scatter entries into private (bucket, block) slices ----
// global offset = cnt[i] + boffs[i >> 10]  (scan3 folded in)
__global__ __launch_bounds__(256) void k_scatter(const int* __restrict__ eidx,
                                                 const int* __restrict__ cofs,
                                                 const int* __restrict__ boffs,
                                                 unsigned* __restrict__ entries) {
    __shared__ int lcur[NBUCK];
    int g = blockIdx.x, tid = threadIdx.x;
    for (int b = tid; b < NBUCK; b += 256) {
        int idx = b * P + g;
        lcur[b] = cofs[idx] + boffs[idx >> 10];
    }
    __syncthreads();
    const int4* r4 = (const int4*)eidx;
    const int4* c4 = (const int4*)(eidx + NUM_EDGES);
    int lo = g * CE4, hi = min(E4, lo + CE4);
    for (int j = lo + tid; j < hi; j += 256) {
        int4 a = r4[j], b = c4[j];
        int rr[4] = {a.x, a.y, a.z, a.w};
        int cc[4] = {b.x, b.y, b.z, b.w};
        #pragma unroll
        for (int q = 0; q < 4; ++q) {
            unsigned r = (unsigned)rr[q], c = (unsigned)cc[q];
            unsigned br = buck(r), bc = buck(c);
            unsigned lr = r - br * BNODE, lc = c - bc * BNODE;
            int p = atomicAdd(&lcur[br], 1);
            entries[p] = (lr << 18) | c;           // nbr raw id < 2^18
            int p2 = atomicAdd(&lcur[bc], 1);
            entries[p2] = (lc << 18) | r;
        }
    }
}

// ---- D) entry-centric bucket gather ----
// Block = one bucket (147 nodes). 8 lanes per entry: lane s loads 16 B
// (cols s*8..s*8+7) of the neighbor's fp16 row and ds_add_f32's into the
// bucket's LDS accumulator. 1-deep software pipeline on (entry, row).
template <bool OUT_HALF>
__global__ __launch_bounds__(512) void k_gat(const unsigned* __restrict__ entries,
                                             const int* __restrict__ cofs,
                                             const int* __restrict__ boffs,
                                             const __half* __restrict__ src,
                                             void* __restrict__ dst) {
    __shared__ float4 acc4[ACC4];                  // ~38.3 KB
    float* acc = (float*)acc4;
    int b = blockIdx.x, tid = threadIdx.x;

    for (int i = tid; i < ACC4; i += 512)
        acc4[i] = make_float4(0.f, 0.f, 0.f, 0.f);

    int i0 = b * P;
    int gbase = cofs[i0] + boffs[i0 >> 10];
    int gnext = 2 * NUM_EDGES;
    if (b + 1 < NBUCK) {
        int i1 = i0 + P;
        gnext = cofs[i1] + boffs[i1 >> 10];
    }
    int cnt = gnext - gbase;
    const unsigned* eb = entries + gbase;
    const h8vec* tv = (const h8vec*)src;
    __syncthreads();

    int s = tid & 7;                               // col group 0..7
    int kk = tid >> 3;                             // entry slot 0..63
    int s8 = s * 8;

    int k = kk;
    if (k < cnt) {
        unsigned e = eb[k];
        h8vec r = tv[(size_t)(e & 0x3FFFFu) * 8 + s];
        for (k += 64; k < cnt; k += 64) {
            unsigned e2 = eb[k];                   // prefetch next entry
            h8vec r2 = tv[(size_t)(e2 & 0x3FFFFu) * 8 + s];   // next row
            int cb = (int)(e >> 18) * ASTRIDE + s8;
            float2 f0 = __half22float2(r.h[0]);
            float2 f1 = __half22float2(r.h[1]);
            float2 f2 = __half22float2(r.h[2]);
            float2 f3 = __half22float2(r.h[3]);
            atomicAdd(&acc[cb + 0], f0.x);
            atomicAdd(&acc[cb + 1], f0.y);
            atomicAdd(&acc[cb + 2], f1.x);
            atomicAdd(&acc[cb + 3], f1.y);
            atomicAdd(&acc[cb + 4], f2.x);
            atomicAdd(&acc[cb + 5], f2.y);
            atomicAdd(&acc[cb + 6], f3.x);
            atomicAdd(&acc[cb + 7], f3.y);
            e = e2; r = r2;
        }
        int cb = (int)(e >> 18) * ASTRIDE + s8;
        float2 f0 = __half22float2(r.h[0]);
        float2 f1 = __half22float2(r.h[1]);
        float2 f2 = __half22float2(r.h[2]);
        float2 f3 = __half22float2(r.h[3]);
        atomicAdd(&acc[cb + 0], f0.x);
        atomicAdd(&acc[cb + 1], f0.y);
        atomicAdd(&acc[cb + 2], f1.x);
        atomicAdd(&acc[cb + 3], f1.y);
        atomicAdd(&acc[cb + 4], f2.x);
        atomicAdd(&acc[cb + 5], f2.y);
        atomicAdd(&acc[cb + 6], f3.x);
        atomicAdd(&acc[cb + 7], f3.y);
    }
    __syncthreads();

    int nbase = b * BNODE;
    if constexpr (OUT_HALF) {
        __half2* o = (__half2*)dst;
        for (int idx = tid; idx < BNODE * 32; idx += 512) {
            int loc = idx >> 5, cp = idx & 31;
            int node = nbase + loc;
            if (node < N_NODES) {
                int a0 = loc * ASTRIDE + cp * 2;
                o[(size_t)node * 32 + cp] =
                    __floats2half2_rn(0.5f * acc[a0], 0.5f * acc[a0 + 1]);
            }
        }
    } else {
        float* o = (float*)dst;
        for (int idx = tid; idx < BNODE * 64; idx += 512) {
            int loc = idx >> 6, col = idx & 63;
            int node = nbase + loc;
            if (node < N_NODES)
                o[(size_t)node * 64 + col] = 0.5f * acc[loc * ASTRIDE + col];
        }
    }
}

extern "C" void kernel_launch(void* const* d_in, const int* in_sizes, int n_in,
                              void* d_out, int out_size, void* d_ws, size_t ws_size,
                              hipStream_t stream) {
    const int*   eidx = (const int*)d_in[0];     // [2, NUM_EDGES]
    const float* user = (const float*)d_in[1];   // [NUM_USERS, 64]
    const float* item = (const float*)d_in[2];   // [NUM_ITEMS, 64]
    float*       out  = (float*)d_out;           // [N_NODES, 64] fp32

    // fp16 concat table lives in out[0 .. 19.2 MB) — dead once layer 2 writes.
    __half* tab_h = (__half*)out;

    char* ws = (char*)d_ws;
    size_t off = 0;
    auto alloc = [&](size_t bytes) {
        char* p = ws + off;
        off += (bytes + 255) & ~(size_t)255;
        return p;
    };
    // entries live through BOTH gathers — no union with inter_h.
    unsigned* entries = (unsigned*)alloc((size_t)2 * NUM_EDGES * sizeof(unsigned)); // 16 MB
    __half*   inter_h = (__half*)alloc((size_t)N_NODES * EMB_D * sizeof(__half));   // 19.2 MB
    int*      cnt     = (int*)alloc((size_t)NTOT * sizeof(int));                    // 2 MB
    int*      bsums   = (int*)alloc((size_t)SBLK * sizeof(int));
    int*      boffs   = (int*)alloc((size_t)SBLK * sizeof(int));

    // build: count (+concat) -> scan -> scatter
    k_count_concat<<<P + CPYB, 256, 0, stream>>>(eidx, cnt, (const float4*)user,
                                                 (const float4*)item, (h8vec*)tab_h);
    k_scan1<<<SBLK, 256, 0, stream>>>(cnt, bsums);
    k_scan2<<<1, 512, 0, stream>>>(bsums, boffs);
    k_scatter<<<P, 256, 0, stream>>>(eidx, cnt, boffs, entries);

    // 2-layer entry-centric propagation: tab_h (in out) -> inter_h -> out
    k_gat<true><<<NBUCK, 512, 0, stream>>>(entries, cnt, boffs, tab_h, inter_h);
    k_gat<false><<<NBUCK, 512, 0, stream>>>(entries, cnt, boffs, inter_h, out);
}

// Round 5
// 273.214 us; speedup vs baseline: 10.0381x; 10.0381x over previous
//
#include <hip/hip_runtime.h>

// LightGCN 2-layer propagation on MI355X — R14: entry-centric gather with
// INT fixed-point LDS atomics (R13's float LDS atomicAdd replaced).
//
// R13 post-mortem: k_gat 1307 us with VALUBusy 1.4%, HBM 2.3%, bank
// conflicts 0.1% => ~200 cy per LDS atomic. atomicAdd(float*) on LDS is
// not a native fast op; atomicAdd(int*) on __shared__ (used throughout
// k_count/k_scatter at 8M ops in ~us) is. R14 keeps the verified R13
// structure and switches to int32 accumulation:
//   - table = int16 fixed point, scale 2^12 (|x|<=5.5, clamped)
//   - gather: 8 sext + 8 ds_add_u32 per entry (native)
//   - layer-1 epilogue integer-exact: inter16 = (acc+8)>>4  (scale 2^9)
//   - layer-2 epilogue: out_f32 = acc * (1/1024)
// Error: ~3.6e-4 RMS per stored value -> layer-2 max ~8e-3 (fp16 path
// passed at 0.25 absmax).

#define NUM_USERS 100000
#define NUM_ITEMS 50000
#define N_NODES   150000
#define NUM_EDGES 2000000
#define EMB_D     64

#define BNODE  147                                 // nodes per bucket
#define NBUCK  1024                                // 4 blocks/CU at 512 thr
#define MAGIC  29217465u                           // ceil(2^32/147), exact for n<150016
#define P      512                                 // producer blocks
#define E4     (NUM_EDGES / 4)                     // 500000 int4 per edge stream
#define CE4    ((E4 + P - 1) / P)                  // 977 int4 per block
#define NTOT   (NBUCK * P)                         // 524288 = 512 * 1024
#define SBLK   (NTOT / 1024)                       // 512 scan blocks

#define ASTRIDE 65                                 // LDS acc row stride (ints)
#define ACCN    (BNODE * ASTRIDE)                  // 9555 ints = 38.2 KB

#define CPYB   1024                                // concat-convert blocks
#define H8CNT  (N_NODES * (EMB_D / 8))             // 1.2M 16-byte chunks
#define UF4    (NUM_USERS * (EMB_D / 4))           // user float4 count

struct alignas(16) s8vec { short s[8]; };          // 8 int16 = 16 B

__device__ __forceinline__ unsigned buck(unsigned n) {
    return (unsigned)(((unsigned long long)n * MAGIC) >> 32);
}

__device__ __forceinline__ short q12(float x) {
    return (short)__float2int_rn(fminf(fmaxf(x * 4096.f, -32600.f), 32600.f));
}

// ---- A) per-block bucket histogram (int4 edge loads) + int16 concat ----
__global__ __launch_bounds__(256) void k_count_concat(const int* __restrict__ eidx,
                                                      int* __restrict__ cnt,
                                                      const float4* __restrict__ user4,
                                                      const float4* __restrict__ item4,
                                                      s8vec* __restrict__ tab) {
    int g = blockIdx.x, tid = threadIdx.x;
    if (g >= P) {
        int i = (g - P) * 256 + tid;
        const int stride = CPYB * 256;
        for (; i < H8CNT; i += stride) {
            const float4* s = (i * 2 < UF4) ? (user4 + (size_t)i * 2)
                                            : (item4 + ((size_t)i * 2 - UF4));
            float4 a = s[0], b = s[1];
            s8vec o;
            o.s[0] = q12(a.x); o.s[1] = q12(a.y); o.s[2] = q12(a.z); o.s[3] = q12(a.w);
            o.s[4] = q12(b.x); o.s[5] = q12(b.y); o.s[6] = q12(b.z); o.s[7] = q12(b.w);
            tab[i] = o;
        }
        return;
    }
    __shared__ int hist[NBUCK];
    for (int b = tid; b < NBUCK; b += 256) hist[b] = 0;
    __syncthreads();
    const int4* r4 = (const int4*)eidx;
    const int4* c4 = (const int4*)(eidx + NUM_EDGES);
    int lo = g * CE4, hi = min(E4, lo + CE4);
    for (int j = lo + tid; j < hi; j += 256) {
        int4 a = r4[j], b = c4[j];
        atomicAdd(&hist[buck(a.x)], 1);
        atomicAdd(&hist[buck(a.y)], 1);
        atomicAdd(&hist[buck(a.z)], 1);
        atomicAdd(&hist[buck(a.w)], 1);
        atomicAdd(&hist[buck(b.x)], 1);
        atomicAdd(&hist[buck(b.y)], 1);
        atomicAdd(&hist[buck(b.z)], 1);
        atomicAdd(&hist[buck(b.w)], 1);
    }
    __syncthreads();
    for (int b = tid; b < NBUCK; b += 256) cnt[b * P + g] = hist[b];
}

// ---- B1) local exclusive scan: 1024 elems/block (256 thr x 4) ----
__global__ __launch_bounds__(256) void k_scan1(int* __restrict__ cnt,
                                               int* __restrict__ blocksums) {
    __shared__ int lds[256];
    int base = blockIdx.x * 1024 + threadIdx.x * 4;
    int v0 = cnt[base + 0], v1 = cnt[base + 1], v2 = cnt[base + 2], v3 = cnt[base + 3];
    int t = v0 + v1 + v2 + v3;
    lds[threadIdx.x] = t;
    __syncthreads();
    int val = t;
    for (int off = 1; off < 256; off <<= 1) {
        int add = (threadIdx.x >= off) ? lds[threadIdx.x - off] : 0;
        __syncthreads();
        val += add;
        lds[threadIdx.x] = val;
        __syncthreads();
    }
    int run = val - t;
    cnt[base + 0] = run; run += v0;
    cnt[base + 1] = run; run += v1;
    cnt[base + 2] = run; run += v2;
    cnt[base + 3] = run;
    if (threadIdx.x == 255) blocksums[blockIdx.x] = val;
}

// ---- B2) 1-block exclusive scan of 512 partials ----
__global__ __launch_bounds__(512) void k_scan2(const int* __restrict__ blocksums,
                                               int* __restrict__ blockoffs) {
    __shared__ int lds[512];
    int t = threadIdx.x;
    int v = (t < SBLK) ? blocksums[t] : 0;
    lds[t] = v;
    __syncthreads();
    int val = v;
    for (int off = 1; off < 512; off <<= 1) {
        int add = (t >= off) ? lds[t - off] : 0;
        __syncthreads();
        val += add;
        lds[t] = val;
        __syncthreads();
    }
    if (t < SBLK) blockoffs[t] = val - v;
}

// ---- C) scatter entries into private (bucket, block) slices ----
// global offset = cnt[i] + boffs[i >> 10]  (scan3 folded in)
__global__ __launch_bounds__(256) void k_scatter(const int* __restrict__ eidx,
                                                 const int* __restrict__ cofs,
                                                 const int* __restrict__ boffs,
                                                 unsigned* __restrict__ entries) {
    __shared__ int lcur[NBUCK];
    int g = blockIdx.x, tid = threadIdx.x;
    for (int b = tid; b < NBUCK; b += 256) {
        int idx = b * P + g;
        lcur[b] = cofs[idx] + boffs[idx >> 10];
    }
    __syncthreads();
    const int4* r4 = (const int4*)eidx;
    const int4* c4 = (const int4*)(eidx + NUM_EDGES);
    int lo = g * CE4, hi = min(E4, lo + CE4);
    for (int j = lo + tid; j < hi; j += 256) {
        int4 a = r4[j], b = c4[j];
        int rr[4] = {a.x, a.y, a.z, a.w};
        int cc[4] = {b.x, b.y, b.z, b.w};
        #pragma unroll
        for (int q = 0; q < 4; ++q) {
            unsigned r = (unsigned)rr[q], c = (unsigned)cc[q];
            unsigned br = buck(r), bc = buck(c);
            unsigned lr = r - br * BNODE, lc = c - bc * BNODE;
            int p = atomicAdd(&lcur[br], 1);
            entries[p] = (lr << 18) | c;           // nbr raw id < 2^18
            int p2 = atomicAdd(&lcur[bc], 1);
            entries[p2] = (lc << 18) | r;
        }
    }
}

// ---- D) entry-centric bucket gather, int32 LDS accumulation ----
// Block = one bucket (147 nodes). 8 lanes per entry: lane s loads 16 B
// (cols s*8..s*8+7, int16) of the neighbor's row and ds_add_u32's into
// acc[loc][.]. 1-deep software pipeline on (entry, row).
// MODE 0: write inter16 (int16, scale 2^9). MODE 1: write fp32 out.
template <int MODE>
__global__ __launch_bounds__(512) void k_gat(const unsigned* __restrict__ entries,
                                             const int* __restrict__ cofs,
                                             const int* __restrict__ boffs,
                                             const s8vec* __restrict__ tv,
                                             void* __restrict__ dst) {
    __shared__ int acc[ACCN];                      // 38.2 KB
    int b = blockIdx.x, tid = threadIdx.x;

    for (int i = tid; i < ACCN; i += 512) acc[i] = 0;

    int i0 = b * P;
    int gbase = cofs[i0] + boffs[i0 >> 10];
    int gnext = 2 * NUM_EDGES;
    if (b + 1 < NBUCK) {
        int i1 = i0 + P;
        gnext = cofs[i1] + boffs[i1 >> 10];
    }
    int cnt = gnext - gbase;
    const unsigned* eb = entries + gbase;
    __syncthreads();

    int s = tid & 7;                               // col group 0..7
    int kk = tid >> 3;                             // entry slot 0..63
    int s8 = s * 8;

    int k = kk;
    if (k < cnt) {
        unsigned e = eb[k];
        s8vec r = tv[(size_t)(e & 0x3FFFFu) * 8 + s];
        for (k += 64; k < cnt; k += 64) {
            unsigned e2 = eb[k];                   // prefetch next entry
            s8vec r2 = tv[(size_t)(e2 & 0x3FFFFu) * 8 + s];   // next row
            int cb = (int)(e >> 18) * ASTRIDE + s8;
            atomicAdd(&acc[cb + 0], (int)r.s[0]);
            atomicAdd(&acc[cb + 1], (int)r.s[1]);
            atomicAdd(&acc[cb + 2], (int)r.s[2]);
            atomicAdd(&acc[cb + 3], (int)r.s[3]);
            atomicAdd(&acc[cb + 4], (int)r.s[4]);
            atomicAdd(&acc[cb + 5], (int)r.s[5]);
            atomicAdd(&acc[cb + 6], (int)r.s[6]);
            atomicAdd(&acc[cb + 7], (int)r.s[7]);
            e = e2; r = r2;
        }
        int cb = (int)(e >> 18) * ASTRIDE + s8;
        atomicAdd(&acc[cb + 0], (int)r.s[0]);
        atomicAdd(&acc[cb + 1], (int)r.s[1]);
        atomicAdd(&acc[cb + 2], (int)r.s[2]);
        atomicAdd(&acc[cb + 3], (int)r.s[3]);
        atomicAdd(&acc[cb + 4], (int)r.s[4]);
        atomicAdd(&acc[cb + 5], (int)r.s[5]);
        atomicAdd(&acc[cb + 6], (int)r.s[6]);
        atomicAdd(&acc[cb + 7], (int)r.s[7]);
    }
    __syncthreads();

    int nbase = b * BNODE;
    if constexpr (MODE == 0) {
        // inter16 = round(acc / 16): (acc*0.5/2^12)*2^9; pack 2 cols/int
        int* o = (int*)dst;
        for (int idx = tid; idx < BNODE * 32; idx += 512) {
            int loc = idx >> 5, cp = idx & 31;
            int node = nbase + loc;
            if (node < N_NODES) {
                int a0 = loc * ASTRIDE + cp * 2;
                int v0 = (acc[a0] + 8) >> 4;
                int v1 = (acc[a0 + 1] + 8) >> 4;
                o[(size_t)node * 32 + cp] = (v0 & 0xFFFF) | (v1 << 16);
            }
        }
    } else {
        // out = acc * 0.5 / 2^9 = acc / 1024
        float* o = (float*)dst;
        for (int idx = tid; idx < BNODE * 64; idx += 512) {
            int loc = idx >> 6, col = idx & 63;
            int node = nbase + loc;
            if (node < N_NODES)
                o[(size_t)node * 64 + col] = (float)acc[loc * ASTRIDE + col] * (1.f / 1024.f);
        }
    }
}

extern "C" void kernel_launch(void* const* d_in, const int* in_sizes, int n_in,
                              void* d_out, int out_size, void* d_ws, size_t ws_size,
                              hipStream_t stream) {
    const int*   eidx = (const int*)d_in[0];     // [2, NUM_EDGES]
    const float* user = (const float*)d_in[1];   // [NUM_USERS, 64]
    const float* item = (const float*)d_in[2];   // [NUM_ITEMS, 64]
    float*       out  = (float*)d_out;           // [N_NODES, 64] fp32

    // int16 concat table lives in out[0 .. 19.2 MB) — dead once layer 2 writes.
    s8vec* tab16 = (s8vec*)out;

    char* ws = (char*)d_ws;
    size_t off = 0;
    auto alloc = [&](size_t bytes) {
        char* p = ws + off;
        off += (bytes + 255) & ~(size_t)255;
        return p;
    };
    unsigned* entries = (unsigned*)alloc((size_t)2 * NUM_EDGES * sizeof(unsigned)); // 16 MB
    s8vec*    inter16 = (s8vec*)alloc((size_t)N_NODES * 8 * sizeof(s8vec));         // 19.2 MB
    int*      cnt     = (int*)alloc((size_t)NTOT * sizeof(int));                    // 2 MB
    int*      bsums   = (int*)alloc((size_t)SBLK * sizeof(int));
    int*      boffs   = (int*)alloc((size_t)SBLK * sizeof(int));

    // build: count (+int16 concat) -> scan -> scatter
    k_count_concat<<<P + CPYB, 256, 0, stream>>>(eidx, cnt, (const float4*)user,
                                                 (const float4*)item, tab16);
    k_scan1<<<SBLK, 256, 0, stream>>>(cnt, bsums);
    k_scan2<<<1, 512, 0, stream>>>(bsums, boffs);
    k_scatter<<<P, 256, 0, stream>>>(eidx, cnt, boffs, entries);

    // 2-layer entry-centric propagation: tab16 (in out) -> inter16 -> out
    k_gat<0><<<NBUCK, 512, 0, stream>>>(entries, cnt, boffs, tab16, inter16);
    k_gat<1><<<NBUCK, 512, 0, stream>>>(entries, cnt, boffs, inter16, out);
}